// Round 5
// baseline (73.735 us; speedup 1.0000x reference)
//
#include <hip/hip_runtime.h>
#include <hip/hip_bf16.h>
#include <stdint.h>

// PUMA functional model == exact integer GEMM. Proof sketch:
//  - analog = sum_{128 rows} bit{0,1}*slice{0..3} <= 384 < 511 = 2^ADC_BIT-1,
//    integers exact in f32, so the ADC round/clip is the identity.
//  - slice shift-add reassembles wint = clip(rne(|w|*4096),0,65535)  (u16)
//  - stream shift-add reassembles xi = clip(rne(x*4096),-32768,32767) (s16)
//  => per polarity p = sum_i xi*w, |p| < 2^41 (exact int64), then
//     q(v) = clamp(rne(v/4096),-32768,32767)*2^-12 per polarity,
//     out = q(p) - q(n) + bias (f32).
//
// Exactness without data assumptions: w split into u8 limbs (wl, wh).
//  |xi|<=2^15, limb<=255 -> |term| <= 8,355,840; a 128-term chunk
//  <= 1.07e9 < 2^31, so int32 / v_dot2_i32_i16 accumulation per chunk is
//  exact; widen to int64 per chunk, reduce chunks in LDS.
//
// ws: [0,4MB)    packedW u32 [i][o]  (pl | ph<<8 | nl<<16 | nh<<24)
//     [4MB,+128K) xq u32 [b/2][ipair][b%2] = x(b,2p) | x(b,2p+1)<<16 (s16 pair)

#define WS_XQ_OFF (4u * 1024u * 1024u)

typedef short short2v __attribute__((ext_vector_type(2)));

__device__ __forceinline__ uint32_t packw(float w) {
    float p = __builtin_rintf(fmaxf(w, 0.0f) * 4096.0f);
    float n = __builtin_rintf(fmaxf(-w, 0.0f) * 4096.0f);
    p = fminf(p, 65535.0f);
    n = fminf(n, 65535.0f);
    return (uint32_t)p | ((uint32_t)n << 16);   // bytes: pl, ph, nl, nh
}

__device__ __forceinline__ int qx(float v) {
    float q = __builtin_rintf(v * 4096.0f);
    return (int)fminf(fmaxf(q, -32768.0f), 32767.0f);
}

// Blocks 0..255: one 64(o) x 64(i) weight tile -> packedW[i][o].
// Blocks 256..271: quantize 4 rows of x -> 2-row tiles xq[b/2][pair][b%2].
__global__ __launch_bounds__(256) void quant_kernel(
        const float* __restrict__ w, const float* __restrict__ x,
        uint32_t* __restrict__ packedW, uint32_t* __restrict__ xq) {
    const int bid = blockIdx.x;
    const int tid = threadIdx.x;
    if (bid < 256) {
        __shared__ uint32_t lds[64][69];   // [o][i]; read banks (5*o+i)%32
        const int to = (bid >> 4) * 64;    // o tile base
        const int ti = (bid & 15) * 64;    // i tile base
        const int r = tid >> 4;            // 0..15
        const int c = (tid & 15) * 4;      // 0..60
        #pragma unroll
        for (int it = 0; it < 4; ++it) {
            const int ol = r + it * 16;
            const float4 wv = *(const float4*)(w + (size_t)(to + ol) * 1024 + ti + c);
            lds[ol][c + 0] = packw(wv.x);
            lds[ol][c + 1] = packw(wv.y);
            lds[ol][c + 2] = packw(wv.z);
            lds[ol][c + 3] = packw(wv.w);
        }
        __syncthreads();
        const int ol = tid & 63;           // lane -> o (coalesced global write)
        const int wq = tid >> 6;           // wave quarter 0..3
        #pragma unroll
        for (int it = 0; it < 16; ++it) {
            const int il = wq + it * 4;
            packedW[(size_t)(ti + il) * 1024 + to + ol] = lds[ol][il];
        }
    } else {
        const int xb = bid - 256;          // 0..15: rows 4xb .. 4xb+3
        uint32_t* __restrict__ dst0 = xq + (size_t)(xb * 2 + 0) * 1024;
        uint32_t* __restrict__ dst1 = xq + (size_t)(xb * 2 + 1) * 1024;
        #pragma unroll
        for (int pp = 0; pp < 2; ++pp) {
            const int p = pp * 256 + tid;  // pair index 0..511
            uint32_t v0, v1, v2, v3;
            {
                const float2 a = *(const float2*)(x + (size_t)(xb * 4 + 0) * 1024 + p * 2);
                v0 = ((uint32_t)qx(a.x) & 0xFFFFu) | ((uint32_t)qx(a.y) << 16);
            }
            {
                const float2 a = *(const float2*)(x + (size_t)(xb * 4 + 1) * 1024 + p * 2);
                v1 = ((uint32_t)qx(a.x) & 0xFFFFu) | ((uint32_t)qx(a.y) << 16);
            }
            {
                const float2 a = *(const float2*)(x + (size_t)(xb * 4 + 2) * 1024 + p * 2);
                v2 = ((uint32_t)qx(a.x) & 0xFFFFu) | ((uint32_t)qx(a.y) << 16);
            }
            {
                const float2 a = *(const float2*)(x + (size_t)(xb * 4 + 3) * 1024 + p * 2);
                v3 = ((uint32_t)qx(a.x) & 0xFFFFu) | ((uint32_t)qx(a.y) << 16);
            }
            *(uint2*)(dst0 + p * 2) = make_uint2(v0, v1);   // rows 4xb+0, +1
            *(uint2*)(dst1 + p * 2) = make_uint2(v2, v3);   // rows 4xb+2, +3
        }
    }
}

// Grid 512 = 16 o-tiles x 32 b-tiles(2 rows); block 512 = 64 o-lanes x
// 8 K-chunks of 128 i (64 pairs). Per thread: 2 batches x {pos,neg} x {lo,hi}
// = 8 int32 accumulators (low reg pressure; __launch_bounds__(512,4) caps 128
// VGPR with est. ~60 -> no spill). Per pair: 2 coalesced W dwords + 1 broadcast
// ds_read_b64 + 4 byte-pair merges + 8 v_dot2_i32_i16 (= 16 limb-MACs).
// o_t = bid & 15 -> all 32 b-tiles of one W slice land on one XCD (L2 reuse).
__global__ __launch_bounds__(512, 4) void mvm_kernel(
        const uint32_t* __restrict__ packedW, const uint32_t* __restrict__ xq,
        const float* __restrict__ bias, float* __restrict__ out) {
    __shared__ int xs[1024];               // [512 pair][2 b] s16 pairs, 4 KB
    __shared__ long long red[4][4][64];    // [b*2+pol][chunk-half][o_l], 8 KB

    const int tid = threadIdx.x;
    const int bid = blockIdx.x;
    const int o_t = bid & 15;
    const int b_t = bid >> 4;              // 0..31 (2 batch rows each)
    const int o_l = tid & 63;
    const int c = tid >> 6;                // K-chunk 0..7
    const int o = o_t * 64 + o_l;

    if (tid < 256)
        *(int4*)(xs + tid * 4) = *(const int4*)((const int*)xq + (size_t)b_t * 1024 + tid * 4);
    __syncthreads();

    const uint32_t* __restrict__ wp = packedW + (size_t)(c * 128) * 1024 + o;
    const int* __restrict__ xp = xs + c * 128;       // 64 pairs * 2 b

    int apl[2] = {0, 0}, aph[2] = {0, 0};
    int anl[2] = {0, 0}, anh[2] = {0, 0};

    #pragma unroll 4
    for (int j = 0; j < 64; ++j) {
        const uint32_t wv0 = wp[(size_t)(j * 2 + 0) * 1024];
        const uint32_t wv1 = wp[(size_t)(j * 2 + 1) * 1024];
        // limb pairs: lo16 = even i (wv0), hi16 = odd i (wv1)
        const uint32_t wPL = (wv0 & 0xFFu)          | ((wv1 & 0xFFu) << 16);
        const uint32_t wPH = ((wv0 >> 8) & 0xFFu)   | (((wv1 >> 8) & 0xFFu) << 16);
        const uint32_t wNL = ((wv0 >> 16) & 0xFFu)  | (((wv1 >> 16) & 0xFFu) << 16);
        const uint32_t wNH = (wv0 >> 24)            | ((wv1 >> 24) << 16);
        const int2 xv = *(const int2*)(xp + j * 2);  // broadcast (wave-uniform)
#if __has_builtin(__builtin_amdgcn_sdot2)
        const short2v sPL = __builtin_bit_cast(short2v, wPL);
        const short2v sPH = __builtin_bit_cast(short2v, wPH);
        const short2v sNL = __builtin_bit_cast(short2v, wNL);
        const short2v sNH = __builtin_bit_cast(short2v, wNH);
        {
            const short2v xa = __builtin_bit_cast(short2v, xv.x);
            apl[0] = __builtin_amdgcn_sdot2(xa, sPL, apl[0], false);
            aph[0] = __builtin_amdgcn_sdot2(xa, sPH, aph[0], false);
            anl[0] = __builtin_amdgcn_sdot2(xa, sNL, anl[0], false);
            anh[0] = __builtin_amdgcn_sdot2(xa, sNH, anh[0], false);
        }
        {
            const short2v xa = __builtin_bit_cast(short2v, xv.y);
            apl[1] = __builtin_amdgcn_sdot2(xa, sPL, apl[1], false);
            aph[1] = __builtin_amdgcn_sdot2(xa, sPH, aph[1], false);
            anl[1] = __builtin_amdgcn_sdot2(xa, sNL, anl[1], false);
            anh[1] = __builtin_amdgcn_sdot2(xa, sNH, anh[1], false);
        }
#else
        // fallback: explicit mul24 limb MACs (exact, i24 operands)
        const int pl0 = (int)(wv0 & 255u), pl1 = (int)(wv1 & 255u);
        const int ph0 = (int)((wv0 >> 8) & 255u), ph1 = (int)((wv1 >> 8) & 255u);
        const int nl0 = (int)((wv0 >> 16) & 255u), nl1 = (int)((wv1 >> 16) & 255u);
        const int nh0 = (int)(wv0 >> 24), nh1 = (int)(wv1 >> 24);
        {
            const int xe = (int)(short)(xv.x & 0xFFFF), xo = xv.x >> 16;
            apl[0] += __mul24(xe, pl0) + __mul24(xo, pl1);
            aph[0] += __mul24(xe, ph0) + __mul24(xo, ph1);
            anl[0] += __mul24(xe, nl0) + __mul24(xo, nl1);
            anh[0] += __mul24(xe, nh0) + __mul24(xo, nh1);
        }
        {
            const int xe = (int)(short)(xv.y & 0xFFFF), xo = xv.y >> 16;
            apl[1] += __mul24(xe, pl0) + __mul24(xo, pl1);
            aph[1] += __mul24(xe, ph0) + __mul24(xo, ph1);
            anl[1] += __mul24(xe, nl0) + __mul24(xo, nl1);
            anh[1] += __mul24(xe, nh0) + __mul24(xo, nh1);
        }
#endif
    }

    long long pp[2], pn[2];
    #pragma unroll
    for (int b = 0; b < 2; ++b) {
        pp[b] = (long long)apl[b] + ((long long)aph[b] << 8);
        pn[b] = (long long)anl[b] + ((long long)anh[b] << 8);
    }

    // two-phase chunk reduction: upper chunks write, lower chunks add
    if (c >= 4) {
        #pragma unroll
        for (int b = 0; b < 2; ++b) {
            red[b * 2 + 0][c - 4][o_l] = pp[b];
            red[b * 2 + 1][c - 4][o_l] = pn[b];
        }
    }
    __syncthreads();
    if (c < 4) {
        #pragma unroll
        for (int b = 0; b < 2; ++b) {
            red[b * 2 + 0][c][o_l] += pp[b];
            red[b * 2 + 1][c][o_l] += pn[b];
        }
    }
    __syncthreads();

    if (tid < 128) {
        const int ro = tid & 63;
        const int rb = tid >> 6;           // batch within 2-row tile
        long long ap = 0, an = 0;
        #pragma unroll
        for (int cc = 0; cc < 4; ++cc) {
            ap += red[rb * 2 + 0][cc][ro];
            an += red[rb * 2 + 1][cc][ro];
        }
        // ACM fixed-point quantization, per polarity, rne (exact in f64)
        double qp = rint((double)ap * (1.0 / 4096.0));
        qp = fmin(fmax(qp, -32768.0), 32767.0);
        double qn = rint((double)an * (1.0 / 4096.0));
        qn = fmin(fmax(qn, -32768.0), 32767.0);
        const int oo = o_t * 64 + ro;
        out[(size_t)(b_t * 2 + rb) * 1024 + oo] =
            (float)((qp - qn) * (1.0 / 4096.0)) + bias[oo];
    }
}

extern "C" void kernel_launch(void* const* d_in, const int* in_sizes, int n_in,
                              void* d_out, int out_size, void* d_ws, size_t ws_size,
                              hipStream_t stream) {
    const float* x    = (const float*)d_in[0];   // [64,1024]
    const float* w    = (const float*)d_in[1];   // [1024,1024]
    const float* bias = (const float*)d_in[2];   // [1024]
    float* out = (float*)d_out;                  // [64,1024]

    uint32_t* packedW = (uint32_t*)d_ws;
    uint32_t* xq = (uint32_t*)((char*)d_ws + WS_XQ_OFF);

    quant_kernel<<<272, 256, 0, stream>>>(w, x, packedW, xq);
    mvm_kernel<<<512, 512, 0, stream>>>(packedW, xq, bias, out);
}

// Round 6
// 72.873 us; speedup vs baseline: 1.0118x; 1.0118x over previous
//
#include <hip/hip_runtime.h>
#include <hip/hip_bf16.h>
#include <stdint.h>

// PUMA functional model == exact integer GEMM. Proof sketch:
//  - analog = sum_{128 rows} bit{0,1}*slice{0..3} <= 384 < 511 = 2^ADC_BIT-1,
//    integers exact in f32, so the ADC round/clip is the identity.
//  - slice shift-add reassembles wint = clip(rne(|w|*4096),0,65535)  (u16)
//  - stream shift-add reassembles xi = clip(rne(x*4096),-32768,32767) (s16)
//  => per polarity p = sum_i xi*w, |p| < 2^41 (exact int64), then
//     q(v) = clamp(rne(v/4096),-32768,32767)*2^-12 per polarity,
//     out = q(p) - q(n) + bias (f32).
//
// Exactness without data assumptions: w split into u8 limbs (wl, wh).
//  |xi|<=2^15, limb<=255 -> |term| <= 8,355,840; a 128-term chunk
//  <= 1.07e9 < 2^31, so int32 / v_dot2_i32_i16 accumulation per chunk is
//  exact; widen to int64 per chunk, reduce chunks in LDS.
//
// ws: [0,4MB)    packedW u32 [i/4][o][i%4]  (pl | ph<<8 | nl<<16 | nh<<24)
//     [4MB,+128K) xq u32 [b/2][ipair][b%2] = x(b,2p) | x(b,2p+1)<<16 (s16 pair)

#define WS_XQ_OFF (4u * 1024u * 1024u)

typedef short short2v __attribute__((ext_vector_type(2)));

__device__ __forceinline__ uint32_t packw(float w) {
    float p = __builtin_rintf(fmaxf(w, 0.0f) * 4096.0f);
    float n = __builtin_rintf(fmaxf(-w, 0.0f) * 4096.0f);
    p = fminf(p, 65535.0f);
    n = fminf(n, 65535.0f);
    return (uint32_t)p | ((uint32_t)n << 16);   // bytes: pl, ph, nl, nh
}

__device__ __forceinline__ int qx(float v) {
    float q = __builtin_rintf(v * 4096.0f);
    return (int)fminf(fmaxf(q, -32768.0f), 32767.0f);
}

// Blocks 0..255: one 64(o) x 64(i) weight tile -> packedW[i/4][o][i%4].
// Blocks 256..271: quantize 4 rows of x -> 2-row tiles xq[b/2][pair][b%2].
__global__ __launch_bounds__(256) void quant_kernel(
        const float* __restrict__ w, const float* __restrict__ x,
        uint32_t* __restrict__ packedW, uint32_t* __restrict__ xq) {
    const int bid = blockIdx.x;
    const int tid = threadIdx.x;
    if (bid < 256) {
        __shared__ uint32_t lds[64][69];   // [o][i]; col reads 2-way alias = free
        const int to = (bid >> 4) * 64;    // o tile base
        const int ti = (bid & 15) * 64;    // i tile base
        const int r = tid >> 4;            // 0..15
        const int c = (tid & 15) * 4;      // 0..60
        #pragma unroll
        for (int it = 0; it < 4; ++it) {
            const int ol = r + it * 16;
            const float4 wv = *(const float4*)(w + (size_t)(to + ol) * 1024 + ti + c);
            lds[ol][c + 0] = packw(wv.x);
            lds[ol][c + 1] = packw(wv.y);
            lds[ol][c + 2] = packw(wv.z);
            lds[ol][c + 3] = packw(wv.w);
        }
        __syncthreads();
        const int ol = tid & 63;           // lane -> o (coalesced uint4 store)
        const int wq = tid >> 6;           // 0..3
        const int ti4 = ti >> 2;           // global i4 base of this tile
        #pragma unroll
        for (int it = 0; it < 4; ++it) {
            const int il4 = wq * 4 + it;   // i4 within tile, 0..15
            uint4 v;
            v.x = lds[ol][il4 * 4 + 0];
            v.y = lds[ol][il4 * 4 + 1];
            v.z = lds[ol][il4 * 4 + 2];
            v.w = lds[ol][il4 * 4 + 3];
            *(uint4*)(packedW + (size_t)(ti4 + il4) * 4096 + (size_t)(to + ol) * 4) = v;
        }
    } else {
        const int xb = bid - 256;          // 0..15: rows 4xb .. 4xb+3
        uint32_t* __restrict__ dst0 = xq + (size_t)(xb * 2 + 0) * 1024;
        uint32_t* __restrict__ dst1 = xq + (size_t)(xb * 2 + 1) * 1024;
        #pragma unroll
        for (int pp = 0; pp < 2; ++pp) {
            const int p = pp * 256 + tid;  // pair index 0..511
            uint32_t v0, v1, v2, v3;
            {
                const float2 a = *(const float2*)(x + (size_t)(xb * 4 + 0) * 1024 + p * 2);
                v0 = ((uint32_t)qx(a.x) & 0xFFFFu) | ((uint32_t)qx(a.y) << 16);
            }
            {
                const float2 a = *(const float2*)(x + (size_t)(xb * 4 + 1) * 1024 + p * 2);
                v1 = ((uint32_t)qx(a.x) & 0xFFFFu) | ((uint32_t)qx(a.y) << 16);
            }
            {
                const float2 a = *(const float2*)(x + (size_t)(xb * 4 + 2) * 1024 + p * 2);
                v2 = ((uint32_t)qx(a.x) & 0xFFFFu) | ((uint32_t)qx(a.y) << 16);
            }
            {
                const float2 a = *(const float2*)(x + (size_t)(xb * 4 + 3) * 1024 + p * 2);
                v3 = ((uint32_t)qx(a.x) & 0xFFFFu) | ((uint32_t)qx(a.y) << 16);
            }
            *(uint2*)(dst0 + p * 2) = make_uint2(v0, v1);   // rows 4xb+0, +1
            *(uint2*)(dst1 + p * 2) = make_uint2(v2, v3);   // rows 4xb+2, +3
        }
    }
}

// Grid 512 = 16 o-tiles x 32 b-tiles(2 rows); block 512 = 64 o-lanes x
// 8 K-chunks of 128 i (32 i4-groups). Per thread: 2 batches x {pos,neg} x
// {lo,hi} = 8 int32 accumulators. Per i4-group: 1 coalesced dwordx4 W load +
// 1 broadcast ds_read_b128 + 8 byte-pair merges + 16 v_dot2_i32_i16
// (= 32 limb-MACs). o_t = bid & 15 -> b-tiles of a W slice share an XCD L2.
__global__ __launch_bounds__(512, 4) void mvm_kernel(
        const uint32_t* __restrict__ packedW, const uint32_t* __restrict__ xq,
        const float* __restrict__ bias, float* __restrict__ out) {
    __shared__ int xs[1024];               // [512 pair][2 b] s16 pairs, 4 KB
    __shared__ long long red[4][4][64];    // [b*2+pol][chunk-half][o_l], 8 KB

    const int tid = threadIdx.x;
    const int bid = blockIdx.x;
    const int o_t = bid & 15;
    const int b_t = bid >> 4;              // 0..31 (2 batch rows each)
    const int o_l = tid & 63;
    const int c = tid >> 6;                // K-chunk 0..7
    const int o = o_t * 64 + o_l;

    if (tid < 256)
        *(int4*)(xs + tid * 4) = *(const int4*)((const int*)xq + (size_t)b_t * 1024 + tid * 4);
    __syncthreads();

    const uint32_t* __restrict__ wp4 = packedW + (size_t)(c * 32) * 4096 + (size_t)o * 4;
    const int* __restrict__ xp = xs + c * 128;       // 64 pairs * 2 b

    int apl[2] = {0, 0}, aph[2] = {0, 0};
    int anl[2] = {0, 0}, anh[2] = {0, 0};

    #pragma unroll 4
    for (int j = 0; j < 32; ++j) {         // i4-group: i = c*128 + 4j + 0..3
        const uint4 wv = *(const uint4*)(wp4 + (size_t)j * 4096);
        // pair 0 = (i0,i1) from wv.x/wv.y; pair 1 = (i2,i3) from wv.z/wv.w
        const uint32_t wPL0 = (wv.x & 0xFFu)         | ((wv.y & 0xFFu) << 16);
        const uint32_t wPH0 = ((wv.x >> 8) & 0xFFu)  | (((wv.y >> 8) & 0xFFu) << 16);
        const uint32_t wNL0 = ((wv.x >> 16) & 0xFFu) | (((wv.y >> 16) & 0xFFu) << 16);
        const uint32_t wNH0 = (wv.x >> 24)           | ((wv.y >> 24) << 16);
        const uint32_t wPL1 = (wv.z & 0xFFu)         | ((wv.w & 0xFFu) << 16);
        const uint32_t wPH1 = ((wv.z >> 8) & 0xFFu)  | (((wv.w >> 8) & 0xFFu) << 16);
        const uint32_t wNL1 = ((wv.z >> 16) & 0xFFu) | (((wv.w >> 16) & 0xFFu) << 16);
        const uint32_t wNH1 = (wv.z >> 24)           | ((wv.w >> 24) << 16);
        // xv = {pair2j.b0, pair2j.b1, pair2j+1.b0, pair2j+1.b1} (wave-uniform)
        const int4 xv = *(const int4*)(xp + j * 4);
#if __has_builtin(__builtin_amdgcn_sdot2)
        const short2v sPL0 = __builtin_bit_cast(short2v, wPL0);
        const short2v sPH0 = __builtin_bit_cast(short2v, wPH0);
        const short2v sNL0 = __builtin_bit_cast(short2v, wNL0);
        const short2v sNH0 = __builtin_bit_cast(short2v, wNH0);
        const short2v sPL1 = __builtin_bit_cast(short2v, wPL1);
        const short2v sPH1 = __builtin_bit_cast(short2v, wPH1);
        const short2v sNL1 = __builtin_bit_cast(short2v, wNL1);
        const short2v sNH1 = __builtin_bit_cast(short2v, wNH1);
        {
            const short2v xa = __builtin_bit_cast(short2v, xv.x);
            const short2v xb = __builtin_bit_cast(short2v, xv.z);
            apl[0] = __builtin_amdgcn_sdot2(xa, sPL0, apl[0], false);
            aph[0] = __builtin_amdgcn_sdot2(xa, sPH0, aph[0], false);
            anl[0] = __builtin_amdgcn_sdot2(xa, sNL0, anl[0], false);
            anh[0] = __builtin_amdgcn_sdot2(xa, sNH0, anh[0], false);
            apl[0] = __builtin_amdgcn_sdot2(xb, sPL1, apl[0], false);
            aph[0] = __builtin_amdgcn_sdot2(xb, sPH1, aph[0], false);
            anl[0] = __builtin_amdgcn_sdot2(xb, sNL1, anl[0], false);
            anh[0] = __builtin_amdgcn_sdot2(xb, sNH1, anh[0], false);
        }
        {
            const short2v xa = __builtin_bit_cast(short2v, xv.y);
            const short2v xb = __builtin_bit_cast(short2v, xv.w);
            apl[1] = __builtin_amdgcn_sdot2(xa, sPL0, apl[1], false);
            aph[1] = __builtin_amdgcn_sdot2(xa, sPH0, aph[1], false);
            anl[1] = __builtin_amdgcn_sdot2(xa, sNL0, anl[1], false);
            anh[1] = __builtin_amdgcn_sdot2(xa, sNH0, anh[1], false);
            apl[1] = __builtin_amdgcn_sdot2(xb, sPL1, apl[1], false);
            aph[1] = __builtin_amdgcn_sdot2(xb, sPH1, aph[1], false);
            anl[1] = __builtin_amdgcn_sdot2(xb, sNL1, anl[1], false);
            anh[1] = __builtin_amdgcn_sdot2(xb, sNH1, anh[1], false);
        }
#else
        // fallback: explicit mul24 limb MACs (exact, i24 operands)
        #pragma unroll
        for (int half = 0; half < 2; ++half) {
            const uint32_t w0 = half ? wv.z : wv.x;
            const uint32_t w1 = half ? wv.w : wv.y;
            const int xpk0 = half ? xv.z : xv.x;   // b0
            const int xpk1 = half ? xv.w : xv.y;   // b1
            const int pl0 = (int)(w0 & 255u), pl1 = (int)(w1 & 255u);
            const int ph0 = (int)((w0 >> 8) & 255u), ph1 = (int)((w1 >> 8) & 255u);
            const int nl0 = (int)((w0 >> 16) & 255u), nl1 = (int)((w1 >> 16) & 255u);
            const int nh0 = (int)(w0 >> 24), nh1 = (int)(w1 >> 24);
            {
                const int xe = (int)(short)(xpk0 & 0xFFFF), xo = xpk0 >> 16;
                apl[0] += __mul24(xe, pl0) + __mul24(xo, pl1);
                aph[0] += __mul24(xe, ph0) + __mul24(xo, ph1);
                anl[0] += __mul24(xe, nl0) + __mul24(xo, nl1);
                anh[0] += __mul24(xe, nh0) + __mul24(xo, nh1);
            }
            {
                const int xe = (int)(short)(xpk1 & 0xFFFF), xo = xpk1 >> 16;
                apl[1] += __mul24(xe, pl0) + __mul24(xo, pl1);
                aph[1] += __mul24(xe, ph0) + __mul24(xo, ph1);
                anl[1] += __mul24(xe, nl0) + __mul24(xo, nl1);
                anh[1] += __mul24(xe, nh0) + __mul24(xo, nh1);
            }
        }
#endif
    }

    long long pp[2], pn[2];
    #pragma unroll
    for (int b = 0; b < 2; ++b) {
        pp[b] = (long long)apl[b] + ((long long)aph[b] << 8);
        pn[b] = (long long)anl[b] + ((long long)anh[b] << 8);
    }

    // two-phase chunk reduction: upper chunks write, lower chunks add
    if (c >= 4) {
        #pragma unroll
        for (int b = 0; b < 2; ++b) {
            red[b * 2 + 0][c - 4][o_l] = pp[b];
            red[b * 2 + 1][c - 4][o_l] = pn[b];
        }
    }
    __syncthreads();
    if (c < 4) {
        #pragma unroll
        for (int b = 0; b < 2; ++b) {
            red[b * 2 + 0][c][o_l] += pp[b];
            red[b * 2 + 1][c][o_l] += pn[b];
        }
    }
    __syncthreads();

    if (tid < 128) {
        const int ro = tid & 63;
        const int rb = tid >> 6;           // batch within 2-row tile
        long long ap = 0, an = 0;
        #pragma unroll
        for (int cc = 0; cc < 4; ++cc) {
            ap += red[rb * 2 + 0][cc][ro];
            an += red[rb * 2 + 1][cc][ro];
        }
        // ACM fixed-point quantization, per polarity, rne (exact in f64)
        double qp = rint((double)ap * (1.0 / 4096.0));
        qp = fmin(fmax(qp, -32768.0), 32767.0);
        double qn = rint((double)an * (1.0 / 4096.0));
        qn = fmin(fmax(qn, -32768.0), 32767.0);
        const int oo = o_t * 64 + ro;
        out[(size_t)(b_t * 2 + rb) * 1024 + oo] =
            (float)((qp - qn) * (1.0 / 4096.0)) + bias[oo];
    }
}

extern "C" void kernel_launch(void* const* d_in, const int* in_sizes, int n_in,
                              void* d_out, int out_size, void* d_ws, size_t ws_size,
                              hipStream_t stream) {
    const float* x    = (const float*)d_in[0];   // [64,1024]
    const float* w    = (const float*)d_in[1];   // [1024,1024]
    const float* bias = (const float*)d_in[2];   // [1024]
    float* out = (float*)d_out;                  // [64,1024]

    uint32_t* packedW = (uint32_t*)d_ws;
    uint32_t* xq = (uint32_t*)((char*)d_ws + WS_XQ_OFF);

    quant_kernel<<<272, 256, 0, stream>>>(w, x, packedW, xq);
    mvm_kernel<<<512, 512, 0, stream>>>(packedW, xq, bias, out);
}